// Round 21
// baseline (222.185 us; speedup 1.0000x reference)
//
#include <hip/hip_runtime.h>
#include <hip/hip_bf16.h>

// SimVQ: z[16,1024,64] f32, codebook[16384,64] f32, proj_w[64,64] f32, proj_b[64] f32, scale f32
// Outputs (fp32, concat): quantized_st[1048576], vq_loss[1], idx[16384]
// r35 = r29/r34 verified base + FLATTENED arbiter (k_arb -> k_arb1 + k_arb2).
// Arbiter post-mortems: ~45µs across 4 variants; cost = SKEW (total candidate work
// ~18ms-wave over 4096 waves, worst wave ~45µs alone; r32 Occ 9% = tail signature).
// Fix: uniform (token,candidate) pair queue. k_scan emits pairs + inits g_keymax/g_win
// for flagged tokens (overflow cnt>CAP -> separate list, never fires). k_arb1: wave per
// pair computes the bit-identical fp64 key -> relaxed atomicMax(g_keymax, enc64(key))
// (g_topu-proven atomic class, NOT r31's ordered same-address kind). k_arb2: recompute
// (deterministic) -> enc match -> atomicMin(g_win, code). max-then-min-code == serial
// tie rule exactly. k_out selects cnt>=2 ? g_win : slot0. Per-wave work uniform ~3
// pairs/phase. All other kernels byte-identical to verified forms (passes at the 49µs
// 2-phase plateau, invariant to 6 structural attacks; k_out 2048-block; k_prep
// parallel-proj; margin scheme r5-r14: top value + 8e-3 collect + fp64 arbiter).

#define NCODES 16384
#define NTOK   16384
#define DIM    64
#define MARGIN_MFMA 8e-3f
#define CAP    16

typedef __attribute__((ext_vector_type(8))) short bf16x8;
typedef __attribute__((ext_vector_type(4))) float f32x4;
#define GLOBAL_AS __attribute__((address_space(1)))
#define LDS_AS    __attribute__((address_space(3)))

__device__ float  g_qcb[NCODES * DIM];   // 4 MB projected codebook fp32 (gather source)
__device__ short  g_cnb[NCODES * DIM];   // 2 MB l2norm(qcb) bf16 row-major (MFMA B)
__device__ short  g_znb[NTOK * DIM];     // 2 MB l2norm(z)  bf16 row-major (MFMA A)
__device__ unsigned g_topu[NTOK];        // orderable-encoded mfma top-1 value
__device__ int    g_candcnt[NTOK];
__device__ int    g_cand[NTOK * CAP];    // 1 MB candidate slots
__device__ int    g_q[NTOK * CAP];       // 1 MB (tok<<4)|slot pair queue
__device__ int    g_qn;
__device__ int    g_ov[NTOK];            // overflow tokens (cnt>CAP; never fires)
__device__ int    g_ovn;
__device__ unsigned long long g_keymax[NTOK];  // orderable-encoded fp64 best key
__device__ int    g_win[NTOK];           // winner code for flagged tokens
__device__ float  g_partial[2048];       // per-block loss partials

__device__ __forceinline__ float wave_sum64(float v) {
#pragma unroll
  for (int o = 32; o > 0; o >>= 1) v += __shfl_xor(v, o, 64);
  return v;
}
__device__ __forceinline__ short f2bf(float f) {
  __hip_bfloat16 h = __float2bfloat16(f);
  return *reinterpret_cast<short*>(&h);
}
__device__ __forceinline__ float bf2f(short s) {
  __hip_bfloat16 h = *reinterpret_cast<__hip_bfloat16*>(&s);
  return __bfloat162float(h);
}
__device__ __forceinline__ void split8(const float* v, bf16x8& hi, bf16x8& lo) {
#pragma unroll
  for (int i = 0; i < 8; ++i) {
    float f = v[i];
    short h = f2bf(f);
    hi[i] = h;
    lo[i] = f2bf(f - bf2f(h));
  }
}
__device__ __forceinline__ unsigned long long encd(double k) {
  unsigned long long b = (unsigned long long)__double_as_longlong(k);
  return (b & 0x8000000000000000ull) ? ~b : (b | 0x8000000000000000ull);
}

// fp64 key for one candidate (identical math/order to the r24/r29 arbiter body)
#define ARB_KEY(KEYVAR)                                                           \
  {                                                                               \
    double s0 = 0.0, s1 = 0.0, s2 = 0.0, s3 = 0.0;                                \
    _Pragma("unroll") for (int kk = 0; kk < 16; ++kk) {                           \
      s0 = fma(WT[kk * 65 + lane], (double)cbl[wave][kk], s0);                    \
      s1 = fma(WT[(kk + 16) * 65 + lane], (double)cbl[wave][kk + 16], s1);        \
      s2 = fma(WT[(kk + 32) * 65 + lane], (double)cbl[wave][kk + 32], s2);        \
      s3 = fma(WT[(kk + 48) * 65 + lane], (double)cbl[wave][kk + 48], s3);        \
    }                                                                             \
    double qc = ((s0 + s1) + (s2 + s3)) + bj;                                     \
    double s = zj * qc, n2 = qc * qc;                                             \
    _Pragma("unroll") for (int o = 32; o > 0; o >>= 1) {                          \
      s += __shfl_xor(s, o, 64);                                                  \
      n2 += __shfl_xor(n2, o, 64);                                                \
    }                                                                             \
    KEYVAR = s / fmax(sqrt(n2), 1e-12);                                           \
  }

// k_prep (r30 geometry, verified): blocks [0,1024): projection; blocks [1024,2048):
// znorm + zero per-call state (g_qn/g_ovn for the new arbiter).
__global__ __launch_bounds__(256) void k_prep(const float* __restrict__ cb,
                                              const float* __restrict__ pw,
                                              const float* __restrict__ pb,
                                              const float* __restrict__ z) {
  int tid = threadIdx.x;
  int wave = tid >> 6, lane = tid & 63, quad = lane >> 4, col = lane & 15;
  if (blockIdx.x < 1024) {
    __shared__ float pn[4][16];
    int rowBase = blockIdx.x * 16;
    const float* cr = cb + (size_t)(rowBase + col) * 64 + quad * 8;
    bf16x8 ah0, al0, ah1, al1;
    split8(cr, ah0, al0);
    split8(cr + 32, ah1, al1);
    const f32x4 fz = {0.f, 0.f, 0.f, 0.f};
    int j = wave * 16 + col;
    const float* wr = pw + (size_t)j * 64 + quad * 8;
    bf16x8 bh0, bl0, bh1, bl1;
    split8(wr, bh0, bl0);
    split8(wr + 32, bh1, bl1);
    f32x4 d = __builtin_amdgcn_mfma_f32_16x16x32_bf16(ah0, bh0, fz, 0, 0, 0);
    d = __builtin_amdgcn_mfma_f32_16x16x32_bf16(ah1, bh1, d, 0, 0, 0);
    d = __builtin_amdgcn_mfma_f32_16x16x32_bf16(ah0, bl0, d, 0, 0, 0);
    d = __builtin_amdgcn_mfma_f32_16x16x32_bf16(ah1, bl1, d, 0, 0, 0);
    d = __builtin_amdgcn_mfma_f32_16x16x32_bf16(al0, bh0, d, 0, 0, 0);
    d = __builtin_amdgcn_mfma_f32_16x16x32_bf16(al1, bh1, d, 0, 0, 0);
    float bj = pb[j];
    float vals[4], nr[4];
#pragma unroll
    for (int r = 0; r < 4; ++r) {
      float v = d[r] + bj;
      vals[r] = v;
      nr[r] = v * v;
    }
#pragma unroll
    for (int r = 0; r < 4; ++r) {
      float v = nr[r];
      v += __shfl_xor(v, 1, 64);
      v += __shfl_xor(v, 2, 64);
      v += __shfl_xor(v, 4, 64);
      v += __shfl_xor(v, 8, 64);
      nr[r] = v;
      if (col == 0) pn[wave][quad * 4 + r] = v;
    }
    __syncthreads();
#pragma unroll
    for (int r = 0; r < 4; ++r) {
      int row16 = quad * 4 + r;
      float tot = (pn[0][row16] + pn[1][row16]) + (pn[2][row16] + pn[3][row16]);
      float inv = 1.0f / fmaxf(sqrtf(tot), 1e-12f);
      int row = rowBase + row16;
      g_qcb[(size_t)row * 64 + j] = vals[r];
      g_cnb[(size_t)row * 64 + j] = f2bf(vals[r] * inv);
    }
  } else {
    int zb = blockIdx.x - 1024;         // 0..1023
    int zgid = zb * 256 + tid;
    if (zgid < NTOK) { g_topu[zgid] = 0u; g_candcnt[zgid] = 0; }
    if (zgid == 0) { g_qn = 0; g_ovn = 0; }
    int base = zb * 16;                 // 16 rows per block
    int row = base + wave * 4;          // wave owns 4 rows
#pragma unroll
    for (int r = 0; r < 4; ++r) {
      float v = z[(size_t)(row + r) * 64 + lane];
      float tot = wave_sum64(v * v);
      g_znb[(size_t)(row + r) * 64 + lane] = f2bf(v / fmaxf(sqrtf(tot), 1e-12f));
    }
  }
}

// GEMM pass 1 (r26, unchanged): grid 1024 = 64 tokGroups x 16 splits, 4 waves/block,
// wave owns 64 tokens. 8 stages of 128 codes (16KB), double-buffered, global_load_lds
// width-16, XOR-swizzled; ONE barrier/stage.
__global__ __launch_bounds__(256) void k_mfma1() {
  __shared__ __align__(16) short smB[2][8192];
  int tid = threadIdx.x;
  int wave = tid >> 6, lane = tid & 63;
  int quad = lane >> 4, col = lane & 15;
  int tokGroup = blockIdx.x >> 4, split = blockIdx.x & 15;
  int tokBase = tokGroup * 256 + wave * 64;

  const short* za = g_znb + (size_t)(tokBase + col) * 64 + quad * 8;
  bf16x8 A0[4], A1[4];
#pragma unroll
  for (int f = 0; f < 4; ++f) {
    A0[f] = *(const bf16x8*)(za + f * 16 * 64);
    A1[f] = *(const bf16x8*)(za + f * 16 * 64 + 32);
  }
  float m[4][4];
#pragma unroll
  for (int f = 0; f < 4; ++f)
#pragma unroll
    for (int r = 0; r < 4; ++r) m[f][r] = -3.0e38f;

  const char* gsplit = (const char*)(g_cnb + (size_t)split * 1024 * 64);
  int x = col & 7;
  int s0off = ((quad ^ x) << 3);
  int s1off = (((4 | quad) ^ x) << 3);
  int goff[4];
#pragma unroll
  for (int i = 0; i < 4; ++i) {
    int cidx = wave * 256 + i * 64 + lane;
    int row = cidx >> 3, sw = cidx & 7;
    goff[i] = row * 128 + ((sw ^ (row & 7)) << 4);
  }

#pragma unroll
  for (int i = 0; i < 4; ++i)
    __builtin_amdgcn_global_load_lds((const GLOBAL_AS void*)(gsplit + goff[i]),
                                     (LDS_AS void*)(&smB[0][wave * 2048 + i * 512]), 16, 0, 0);
  __syncthreads();

  int p = 0;
  for (int s = 0; s < 8; ++s) {
    if (s < 7) {
      const char* gb = gsplit + (size_t)(s + 1) * 16384;
#pragma unroll
      for (int i = 0; i < 4; ++i)
        __builtin_amdgcn_global_load_lds((const GLOBAL_AS void*)(gb + goff[i]),
                                         (LDS_AS void*)(&smB[p ^ 1][wave * 2048 + i * 512]),
                                         16, 0, 0);
    }
    const short* bufp = smB[p];
#pragma unroll
    for (int h = 0; h < 2; ++h) {
      bf16x8 B0[4], B1[4];
#pragma unroll
      for (int t = 0; t < 4; ++t) {
        const short* lb = bufp + ((h * 4 + t) * 16 + col) * 64;
        B0[t] = *(const bf16x8*)(lb + s0off);
        B1[t] = *(const bf16x8*)(lb + s1off);
      }
#pragma unroll
      for (int t = 0; t < 4; ++t) {
#pragma unroll
        for (int f = 0; f < 4; ++f) {
          f32x4 acc = {0.f, 0.f, 0.f, 0.f};
          acc = __builtin_amdgcn_mfma_f32_16x16x32_bf16(A0[f], B0[t], acc, 0, 0, 0);
          acc = __builtin_amdgcn_mfma_f32_16x16x32_bf16(A1[f], B1[t], acc, 0, 0, 0);
#pragma unroll
          for (int r = 0; r < 4; ++r) m[f][r] = fmaxf(m[f][r], acc[r]);
        }
      }
    }
    __syncthreads();
    p ^= 1;
  }

#pragma unroll
  for (int f = 0; f < 4; ++f)
#pragma unroll
    for (int r = 0; r < 4; ++r) {
      float v = m[f][r];
      v = fmaxf(v, __shfl_xor(v, 1, 64));
      v = fmaxf(v, __shfl_xor(v, 2, 64));
      v = fmaxf(v, __shfl_xor(v, 4, 64));
      v = fmaxf(v, __shfl_xor(v, 8, 64));
      if (col == 0) {
        unsigned b = __float_as_uint(v);
        unsigned e = (b & 0x80000000u) ? ~b : (b | 0x80000000u);
        atomicMax(&g_topu[tokBase + f * 16 + quad * 4 + r], e);
      }
    }
}

// GEMM pass 2 (r26, unchanged): same skeleton; collect candidates within margin.
__global__ __launch_bounds__(256) void k_mfma2() {
  __shared__ __align__(16) short smB[2][8192];
  int tid = threadIdx.x;
  int wave = tid >> 6, lane = tid & 63;
  int quad = lane >> 4, col = lane & 15;
  int tokGroup = blockIdx.x >> 4, split = blockIdx.x & 15;
  int tokBase = tokGroup * 256 + wave * 64;

  const short* za = g_znb + (size_t)(tokBase + col) * 64 + quad * 8;
  bf16x8 A0[4], A1[4];
#pragma unroll
  for (int f = 0; f < 4; ++f) {
    A0[f] = *(const bf16x8*)(za + f * 16 * 64);
    A1[f] = *(const bf16x8*)(za + f * 16 * 64 + 32);
  }
  float th[4][4];
#pragma unroll
  for (int f = 0; f < 4; ++f)
#pragma unroll
    for (int r = 0; r < 4; ++r) {
      unsigned u = g_topu[tokBase + f * 16 + quad * 4 + r];
      unsigned b = (u & 0x80000000u) ? (u & 0x7FFFFFFFu) : ~u;
      th[f][r] = __uint_as_float(b) - MARGIN_MFMA;
    }

  const char* gsplit = (const char*)(g_cnb + (size_t)split * 1024 * 64);
  int x = col & 7;
  int s0off = ((quad ^ x) << 3);
  int s1off = (((4 | quad) ^ x) << 3);
  int goff[4];
#pragma unroll
  for (int i = 0; i < 4; ++i) {
    int cidx = wave * 256 + i * 64 + lane;
    int row = cidx >> 3, sw = cidx & 7;
    goff[i] = row * 128 + ((sw ^ (row & 7)) << 4);
  }

#pragma unroll
  for (int i = 0; i < 4; ++i)
    __builtin_amdgcn_global_load_lds((const GLOBAL_AS void*)(gsplit + goff[i]),
                                     (LDS_AS void*)(&smB[0][wave * 2048 + i * 512]), 16, 0, 0);
  __syncthreads();

  int codeB = split * 1024 + col;
  int p = 0;
  for (int s = 0; s < 8; ++s) {
    if (s < 7) {
      const char* gb = gsplit + (size_t)(s + 1) * 16384;
#pragma unroll
      for (int i = 0; i < 4; ++i)
        __builtin_amdgcn_global_load_lds((const GLOBAL_AS void*)(gb + goff[i]),
                                         (LDS_AS void*)(&smB[p ^ 1][wave * 2048 + i * 512]),
                                         16, 0, 0);
    }
    const short* bufp = smB[p];
#pragma unroll
    for (int h = 0; h < 2; ++h) {
      bf16x8 B0[4], B1[4];
#pragma unroll
      for (int t = 0; t < 4; ++t) {
        const short* lb = bufp + ((h * 4 + t) * 16 + col) * 64;
        B0[t] = *(const bf16x8*)(lb + s0off);
        B1[t] = *(const bf16x8*)(lb + s1off);
      }
#pragma unroll
      for (int t = 0; t < 4; ++t) {
        int code = codeB + s * 128 + (h * 4 + t) * 16;
#pragma unroll
        for (int f = 0; f < 4; ++f) {
          f32x4 acc = {0.f, 0.f, 0.f, 0.f};
          acc = __builtin_amdgcn_mfma_f32_16x16x32_bf16(A0[f], B0[t], acc, 0, 0, 0);
          acc = __builtin_amdgcn_mfma_f32_16x16x32_bf16(A1[f], B1[t], acc, 0, 0, 0);
          float dmax = fmaxf(fmaxf(acc[0] - th[f][0], acc[1] - th[f][1]),
                             fmaxf(acc[2] - th[f][2], acc[3] - th[f][3]));
          if (dmax >= 0.f) {
#pragma unroll
            for (int r = 0; r < 4; ++r) {
              if (acc[r] >= th[f][r]) {
                int tok = tokBase + f * 16 + quad * 4 + r;
                int pos = atomicAdd(&g_candcnt[tok], 1);
                if (pos < CAP) g_cand[tok * CAP + pos] = code;
              }
            }
          }
        }
      }
    }
    __syncthreads();
    p ^= 1;
  }
}

// k_scan (r35): emit (tok,slot) pair queue for flagged tokens + init winner state.
// Prefix sums in LDS, ONE atomicAdd per block per queue. Overflow -> g_ov (never fires).
__global__ __launch_bounds__(256) void k_scan() {
  __shared__ int pcnt[256];
  __shared__ int povf[256];
  __shared__ int qb, ob;
  int tid = threadIdx.x;
  int tok = blockIdx.x * 256 + tid;
  int cnt = g_candcnt[tok];
  int np = 0, ov = 0;
  if (cnt >= 2) {
    if (cnt <= CAP) np = cnt;
    else ov = 1;
    g_keymax[tok] = 0ull;          // below any encoded finite double
    g_win[tok] = 0x7FFFFFFF;
  }
  pcnt[tid] = np;
  povf[tid] = ov;
  __syncthreads();
  if (tid == 0) {
    int run = 0, rov = 0;
    for (int i = 0; i < 256; ++i) {
      int a = pcnt[i]; pcnt[i] = run; run += a;
      int b = povf[i]; povf[i] = rov; rov += b;
    }
    qb = atomicAdd(&g_qn, run);
    ob = atomicAdd(&g_ovn, rov);
  }
  __syncthreads();
  if (np) {
    int base = qb + pcnt[tid];
    for (int i = 0; i < np; ++i) g_q[base + i] = (tok << 4) | i;
  }
  if (ov) g_ov[ob + povf[tid]] = tok;
}

// k_arb1 (r35): 1024 blocks x 4 waves = 4096 waves stride the PAIR queue (uniform cost
// per pair -> no skew). Each wave computes one candidate's fp64 key (bit-identical) and
// lane0 does relaxed atomicMax(g_keymax[tok], enc64(key)). Overflow tokens (never):
// serial full-scan writes g_win directly (exact old rule).
__global__ __launch_bounds__(256) void k_arb1(const float* __restrict__ z,
                                              const float* __restrict__ cb,
                                              const float* __restrict__ pw,
                                              const float* __restrict__ pb) {
  __shared__ double WT[64 * 65];
  __shared__ float cbl[4][64];
  int tid = threadIdx.x;
  int wave = tid >> 6, lane = tid & 63;
  for (int e = tid; e < 4096; e += 256) {
    int j = e >> 6, k = e & 63;
    WT[k * 65 + j] = (double)pw[e];
  }
  __syncthreads();

  int qn = g_qn, ovn = g_ovn;
  double bj = (double)pb[lane];
  int gwave = blockIdx.x * 4 + wave;

  for (int p = gwave; p < qn; p += 4096) {
    int e = g_q[p];
    int tok = e >> 4, slot = e & 15;
    int code = g_cand[tok * CAP + slot];
    double zj = (double)z[(size_t)tok * 64 + lane];
    cbl[wave][lane] = cb[(size_t)code * 64 + lane];
    double key;
    ARB_KEY(key);
    if (lane == 0) atomicMax(&g_keymax[tok], encd(key));
  }
  for (int o = gwave; o < ovn; o += 4096) {  // insurance; empirically never
    int tok = g_ov[o];
    double zj = (double)z[(size_t)tok * 64 + lane];
    double best = -1.0e300;
    int bi = 0x7FFFFFFF;
    for (int code = 0; code < NCODES; ++code) {
      cbl[wave][lane] = cb[(size_t)code * 64 + lane];
      double key;
      ARB_KEY(key);
      if (key > best || (key == best && code < bi)) { best = key; bi = code; }
    }
    if (lane == 0) g_win[tok] = bi;
  }
}

// k_arb2 (r35): same geometry; recompute each pair's key (deterministic, bit-identical
// to arb1) and atomicMin the code into g_win where it equals the token's max key.
__global__ __launch_bounds__(256) void k_arb2(const float* __restrict__ z,
                                              const float* __restrict__ cb,
                                              const float* __restrict__ pw,
                                              const float* __restrict__ pb) {
  __shared__ double WT[64 * 65];
  __shared__ float cbl[4][64];
  int tid = threadIdx.x;
  int wave = tid >> 6, lane = tid & 63;
  for (int e = tid; e < 4096; e += 256) {
    int j = e >> 6, k = e & 63;
    WT[k * 65 + j] = (double)pw[e];
  }
  __syncthreads();

  int qn = g_qn;
  double bj = (double)pb[lane];
  int gwave = blockIdx.x * 4 + wave;

  for (int p = gwave; p < qn; p += 4096) {
    int e = g_q[p];
    int tok = e >> 4, slot = e & 15;
    int code = g_cand[tok * CAP + slot];
    double zj = (double)z[(size_t)tok * 64 + lane];
    cbl[wave][lane] = cb[(size_t)code * 64 + lane];
    double key;
    ARB_KEY(key);
    if (lane == 0 && encd(key) == g_keymax[tok]) atomicMin(&g_win[tok], code);
  }
}

// k_out (r35): r29 geometry (2048 blocks x 4 waves, 2 tokens/wave); winner = cnt>=2 ?
// g_win : slot0. PLAIN stores only.
__global__ __launch_bounds__(256) void k_out(const float* __restrict__ z,
                                             float* __restrict__ out0,
                                             float* __restrict__ out2) {
  __shared__ float ws[4];
  int tid = threadIdx.x;
  int wave = tid >> 6, lane = tid & 63;
  int base = blockIdx.x * 8 + wave * 2;
  int c0 = g_candcnt[base];
  int c1 = g_candcnt[base + 1];
  int i0 = (c0 >= 2) ? g_win[base] : g_cand[(size_t)base * CAP];
  int i1 = (c1 >= 2) ? g_win[base + 1] : g_cand[(size_t)(base + 1) * CAP];
  float q0 = g_qcb[(size_t)i0 * 64 + lane];
  float z0 = z[(size_t)base * 64 + lane];
  float q1 = g_qcb[(size_t)i1 * 64 + lane];
  float z1 = z[(size_t)(base + 1) * 64 + lane];
  float d0 = q0 - z0;
  float d1 = q1 - z1;
  out0[(size_t)base * 64 + lane] = z0 + d0;        // z + (q - z), ref op order
  out0[(size_t)(base + 1) * 64 + lane] = z1 + d1;
  if (lane == 0) {
    out2[base] = (float)i0;
    out2[base + 1] = (float)i1;
  }
  float lsum = fmaf(d0, d0, d1 * d1);
  float tot = wave_sum64(lsum);
  if (lane == 0) ws[wave] = tot;
  __syncthreads();
  if (tid == 0) g_partial[blockIdx.x] = ((ws[0] + ws[1]) + (ws[2] + ws[3]));
}

// k_loss (r29, unchanged): one wave sums the 2048 partials in fixed order -> out1.
__global__ void k_loss(float* __restrict__ out1) {
  int lane = threadIdx.x;
  float s = 0.f;
#pragma unroll
  for (int i = 0; i < 32; ++i) s += g_partial[lane + 64 * i];
  s = wave_sum64(s);
  if (lane == 0) out1[0] = 1.25f * s / 1048576.0f;  // commitment == codebook numerically
}

extern "C" void kernel_launch(void* const* d_in, const int* in_sizes, int n_in,
                              void* d_out, int out_size, void* d_ws, size_t ws_size,
                              hipStream_t stream) {
  const float* z = (const float*)d_in[0];
  const float* cb = (const float*)d_in[1];
  const float* pw = (const float*)d_in[2];
  const float* pb = (const float*)d_in[3];
  // d_in[4] (scale) unused: argmin invariant to positive scale

  float* out0 = (float*)d_out;
  float* out1 = out0 + (size_t)NTOK * DIM;
  float* out2 = out1 + 1;

  hipLaunchKernelGGL(k_prep, dim3(2048), dim3(256), 0, stream, cb, pw, pb, z);
  hipLaunchKernelGGL(k_mfma1, dim3(1024), dim3(256), 0, stream);
  hipLaunchKernelGGL(k_mfma2, dim3(1024), dim3(256), 0, stream);
  hipLaunchKernelGGL(k_scan, dim3(64), dim3(256), 0, stream);
  hipLaunchKernelGGL(k_arb1, dim3(1024), dim3(256), 0, stream, z, cb, pw, pb);
  hipLaunchKernelGGL(k_arb2, dim3(1024), dim3(256), 0, stream, z, cb, pw, pb);
  hipLaunchKernelGGL(k_out, dim3(2048), dim3(256), 0, stream, z, out0, out2);
  hipLaunchKernelGGL(k_loss, dim3(1), dim3(64), 0, stream, out1);
}

// Round 22
// 188.662 us; speedup vs baseline: 1.1777x; 1.1777x over previous
//
#include <hip/hip_runtime.h>
#include <hip/hip_bf16.h>

// SimVQ: z[16,1024,64] f32, codebook[16384,64] f32, proj_w[64,64] f32, proj_b[64] f32, scale f32
// Outputs (fp32, concat): quantized_st[1048576], vq_loss[1], idx[16384]
// r36 = r34 byte-exact RESTORE (verified 189.5µs, tied best with r29's 189.2).
// r35 post-mortem: flattened two-phase arbiter = +33µs (double key work + extra launch);
// FIFTH arbiter variant at/above the ~45µs wave-per-token floor -> arbiter exhausted.
// Session plateau evidence: passes 49.5µs x8 structural variants; arbiter ~45µs x5
// variants; fusion refuted x3; geometry bumps exhausted. 189µs = 2x49.5 (2-phase GEMM
// issue floor) + ~45 (fp64 arbiter floor) + ~25 (tail latency floors) + ~20 gaps.
// Margin scheme proven r5-r14: pass1 mfma top value, pass2 collect within 8e-3
// (bf16 quant err <= 4e-3 + Ozaki proj err ~1e-5), fp64 arbiter on cnt>=2 tokens.

#define NCODES 16384
#define NTOK   16384
#define DIM    64
#define MARGIN_MFMA 8e-3f
#define CAP    16

typedef __attribute__((ext_vector_type(8))) short bf16x8;
typedef __attribute__((ext_vector_type(4))) float f32x4;
#define GLOBAL_AS __attribute__((address_space(1)))
#define LDS_AS    __attribute__((address_space(3)))

__device__ float  g_qcb[NCODES * DIM];   // 4 MB projected codebook fp32 (gather source)
__device__ short  g_cnb[NCODES * DIM];   // 2 MB l2norm(qcb) bf16 row-major (MFMA B)
__device__ short  g_znb[NTOK * DIM];     // 2 MB l2norm(z)  bf16 row-major (MFMA A)
__device__ unsigned g_topu[NTOK];        // orderable-encoded mfma top-1 value
__device__ int    g_candcnt[NTOK];
__device__ int    g_cand[NTOK * CAP];    // 1 MB; slot 0 holds the winner after k_arb
__device__ int    g_wl[NTOK];            // flagged-token worklist
__device__ int    g_wln;
__device__ float  g_partial[2048];       // per-block loss partials (all written every call)

__device__ __forceinline__ float wave_sum64(float v) {
#pragma unroll
  for (int o = 32; o > 0; o >>= 1) v += __shfl_xor(v, o, 64);
  return v;
}
__device__ __forceinline__ short f2bf(float f) {
  __hip_bfloat16 h = __float2bfloat16(f);
  return *reinterpret_cast<short*>(&h);
}
__device__ __forceinline__ float bf2f(short s) {
  __hip_bfloat16 h = *reinterpret_cast<__hip_bfloat16*>(&s);
  return __bfloat162float(h);
}
__device__ __forceinline__ void split8(const float* v, bf16x8& hi, bf16x8& lo) {
#pragma unroll
  for (int i = 0; i < 8; ++i) {
    float f = v[i];
    short h = f2bf(f);
    hi[i] = h;
    lo[i] = f2bf(f - bf2f(h));
  }
}
// asm load: compiler cannot sink it; we own the waits (r20-proven).
__device__ __forceinline__ void gld_f32(float& dst, const float* addr) {
  asm volatile("global_load_dword %0, %1, off" : "=v"(dst) : "v"(addr));
}
#define WAITV0                                            \
  do {                                                    \
    asm volatile("s_waitcnt vmcnt(0)" ::: "memory");      \
    __builtin_amdgcn_sched_barrier(0);                    \
  } while (0)

// k_prep (r30 geometry, verified): blocks [0,1024): projection, block owns 16 cb rows,
// wave w owns col-tile j in [16w,16w+16); cross-wave norm via pn[4][16] + 1 barrier.
// blocks [1024,2048): znorm + zero per-call state (incl. g_wln for k_scan).
__global__ __launch_bounds__(256) void k_prep(const float* __restrict__ cb,
                                              const float* __restrict__ pw,
                                              const float* __restrict__ pb,
                                              const float* __restrict__ z) {
  int tid = threadIdx.x;
  int wave = tid >> 6, lane = tid & 63, quad = lane >> 4, col = lane & 15;
  if (blockIdx.x < 1024) {
    __shared__ float pn[4][16];
    int rowBase = blockIdx.x * 16;
    const float* cr = cb + (size_t)(rowBase + col) * 64 + quad * 8;
    bf16x8 ah0, al0, ah1, al1;
    split8(cr, ah0, al0);
    split8(cr + 32, ah1, al1);
    const f32x4 fz = {0.f, 0.f, 0.f, 0.f};
    int j = wave * 16 + col;
    const float* wr = pw + (size_t)j * 64 + quad * 8;
    bf16x8 bh0, bl0, bh1, bl1;
    split8(wr, bh0, bl0);
    split8(wr + 32, bh1, bl1);
    f32x4 d = __builtin_amdgcn_mfma_f32_16x16x32_bf16(ah0, bh0, fz, 0, 0, 0);
    d = __builtin_amdgcn_mfma_f32_16x16x32_bf16(ah1, bh1, d, 0, 0, 0);
    d = __builtin_amdgcn_mfma_f32_16x16x32_bf16(ah0, bl0, d, 0, 0, 0);
    d = __builtin_amdgcn_mfma_f32_16x16x32_bf16(ah1, bl1, d, 0, 0, 0);
    d = __builtin_amdgcn_mfma_f32_16x16x32_bf16(al0, bh0, d, 0, 0, 0);
    d = __builtin_amdgcn_mfma_f32_16x16x32_bf16(al1, bh1, d, 0, 0, 0);
    float bj = pb[j];
    float vals[4], nr[4];
#pragma unroll
    for (int r = 0; r < 4; ++r) {
      float v = d[r] + bj;
      vals[r] = v;
      nr[r] = v * v;
    }
#pragma unroll
    for (int r = 0; r < 4; ++r) {
      float v = nr[r];
      v += __shfl_xor(v, 1, 64);
      v += __shfl_xor(v, 2, 64);
      v += __shfl_xor(v, 4, 64);
      v += __shfl_xor(v, 8, 64);
      nr[r] = v;
      if (col == 0) pn[wave][quad * 4 + r] = v;
    }
    __syncthreads();
#pragma unroll
    for (int r = 0; r < 4; ++r) {
      int row16 = quad * 4 + r;
      float tot = (pn[0][row16] + pn[1][row16]) + (pn[2][row16] + pn[3][row16]);
      float inv = 1.0f / fmaxf(sqrtf(tot), 1e-12f);
      int row = rowBase + row16;
      g_qcb[(size_t)row * 64 + j] = vals[r];
      g_cnb[(size_t)row * 64 + j] = f2bf(vals[r] * inv);
    }
  } else {
    int zb = blockIdx.x - 1024;         // 0..1023
    int zgid = zb * 256 + tid;
    if (zgid < NTOK) { g_topu[zgid] = 0u; g_candcnt[zgid] = 0; }
    if (zgid == 0) g_wln = 0;
    int base = zb * 16;                 // 16 rows per block
    int row = base + wave * 4;          // wave owns 4 rows
#pragma unroll
    for (int r = 0; r < 4; ++r) {
      float v = z[(size_t)(row + r) * 64 + lane];
      float tot = wave_sum64(v * v);
      g_znb[(size_t)(row + r) * 64 + lane] = f2bf(v / fmaxf(sqrtf(tot), 1e-12f));
    }
  }
}

// GEMM pass 1 (r26, unchanged): grid 1024 = 64 tokGroups x 16 splits, 4 waves/block,
// wave owns 64 tokens (4 f-groups). Split = 1024 codes, 8 stages of 128 codes (16KB),
// double-buffered, global_load_lds width-16, XOR-swizzled; ONE barrier/stage.
__global__ __launch_bounds__(256) void k_mfma1() {
  __shared__ __align__(16) short smB[2][8192];
  int tid = threadIdx.x;
  int wave = tid >> 6, lane = tid & 63;
  int quad = lane >> 4, col = lane & 15;
  int tokGroup = blockIdx.x >> 4, split = blockIdx.x & 15;
  int tokBase = tokGroup * 256 + wave * 64;

  const short* za = g_znb + (size_t)(tokBase + col) * 64 + quad * 8;
  bf16x8 A0[4], A1[4];
#pragma unroll
  for (int f = 0; f < 4; ++f) {
    A0[f] = *(const bf16x8*)(za + f * 16 * 64);
    A1[f] = *(const bf16x8*)(za + f * 16 * 64 + 32);
  }
  float m[4][4];
#pragma unroll
  for (int f = 0; f < 4; ++f)
#pragma unroll
    for (int r = 0; r < 4; ++r) m[f][r] = -3.0e38f;

  const char* gsplit = (const char*)(g_cnb + (size_t)split * 1024 * 64);
  int x = col & 7;
  int s0off = ((quad ^ x) << 3);
  int s1off = (((4 | quad) ^ x) << 3);
  int goff[4];
#pragma unroll
  for (int i = 0; i < 4; ++i) {
    int cidx = wave * 256 + i * 64 + lane;
    int row = cidx >> 3, sw = cidx & 7;
    goff[i] = row * 128 + ((sw ^ (row & 7)) << 4);
  }

#pragma unroll
  for (int i = 0; i < 4; ++i)
    __builtin_amdgcn_global_load_lds((const GLOBAL_AS void*)(gsplit + goff[i]),
                                     (LDS_AS void*)(&smB[0][wave * 2048 + i * 512]), 16, 0, 0);
  __syncthreads();

  int p = 0;
  for (int s = 0; s < 8; ++s) {
    if (s < 7) {
      const char* gb = gsplit + (size_t)(s + 1) * 16384;
#pragma unroll
      for (int i = 0; i < 4; ++i)
        __builtin_amdgcn_global_load_lds((const GLOBAL_AS void*)(gb + goff[i]),
                                         (LDS_AS void*)(&smB[p ^ 1][wave * 2048 + i * 512]),
                                         16, 0, 0);
    }
    const short* bufp = smB[p];
#pragma unroll
    for (int h = 0; h < 2; ++h) {
      bf16x8 B0[4], B1[4];
#pragma unroll
      for (int t = 0; t < 4; ++t) {
        const short* lb = bufp + ((h * 4 + t) * 16 + col) * 64;
        B0[t] = *(const bf16x8*)(lb + s0off);
        B1[t] = *(const bf16x8*)(lb + s1off);
      }
#pragma unroll
      for (int t = 0; t < 4; ++t) {
#pragma unroll
        for (int f = 0; f < 4; ++f) {
          f32x4 acc = {0.f, 0.f, 0.f, 0.f};
          acc = __builtin_amdgcn_mfma_f32_16x16x32_bf16(A0[f], B0[t], acc, 0, 0, 0);
          acc = __builtin_amdgcn_mfma_f32_16x16x32_bf16(A1[f], B1[t], acc, 0, 0, 0);
#pragma unroll
          for (int r = 0; r < 4; ++r) m[f][r] = fmaxf(m[f][r], acc[r]);
        }
      }
    }
    __syncthreads();
    p ^= 1;
  }

#pragma unroll
  for (int f = 0; f < 4; ++f)
#pragma unroll
    for (int r = 0; r < 4; ++r) {
      float v = m[f][r];
      v = fmaxf(v, __shfl_xor(v, 1, 64));
      v = fmaxf(v, __shfl_xor(v, 2, 64));
      v = fmaxf(v, __shfl_xor(v, 4, 64));
      v = fmaxf(v, __shfl_xor(v, 8, 64));
      if (col == 0) {
        unsigned b = __float_as_uint(v);
        unsigned e = (b & 0x80000000u) ? ~b : (b | 0x80000000u);
        atomicMax(&g_topu[tokBase + f * 16 + quad * 4 + r], e);
      }
    }
}

// GEMM pass 2 (r26, unchanged): same 16-split/8-stage skeleton; collect candidates.
__global__ __launch_bounds__(256) void k_mfma2() {
  __shared__ __align__(16) short smB[2][8192];
  int tid = threadIdx.x;
  int wave = tid >> 6, lane = tid & 63;
  int quad = lane >> 4, col = lane & 15;
  int tokGroup = blockIdx.x >> 4, split = blockIdx.x & 15;
  int tokBase = tokGroup * 256 + wave * 64;

  const short* za = g_znb + (size_t)(tokBase + col) * 64 + quad * 8;
  bf16x8 A0[4], A1[4];
#pragma unroll
  for (int f = 0; f < 4; ++f) {
    A0[f] = *(const bf16x8*)(za + f * 16 * 64);
    A1[f] = *(const bf16x8*)(za + f * 16 * 64 + 32);
  }
  float th[4][4];
#pragma unroll
  for (int f = 0; f < 4; ++f)
#pragma unroll
    for (int r = 0; r < 4; ++r) {
      unsigned u = g_topu[tokBase + f * 16 + quad * 4 + r];
      unsigned b = (u & 0x80000000u) ? (u & 0x7FFFFFFFu) : ~u;
      th[f][r] = __uint_as_float(b) - MARGIN_MFMA;
    }

  const char* gsplit = (const char*)(g_cnb + (size_t)split * 1024 * 64);
  int x = col & 7;
  int s0off = ((quad ^ x) << 3);
  int s1off = (((4 | quad) ^ x) << 3);
  int goff[4];
#pragma unroll
  for (int i = 0; i < 4; ++i) {
    int cidx = wave * 256 + i * 64 + lane;
    int row = cidx >> 3, sw = cidx & 7;
    goff[i] = row * 128 + ((sw ^ (row & 7)) << 4);
  }

#pragma unroll
  for (int i = 0; i < 4; ++i)
    __builtin_amdgcn_global_load_lds((const GLOBAL_AS void*)(gsplit + goff[i]),
                                     (LDS_AS void*)(&smB[0][wave * 2048 + i * 512]), 16, 0, 0);
  __syncthreads();

  int codeB = split * 1024 + col;
  int p = 0;
  for (int s = 0; s < 8; ++s) {
    if (s < 7) {
      const char* gb = gsplit + (size_t)(s + 1) * 16384;
#pragma unroll
      for (int i = 0; i < 4; ++i)
        __builtin_amdgcn_global_load_lds((const GLOBAL_AS void*)(gb + goff[i]),
                                         (LDS_AS void*)(&smB[p ^ 1][wave * 2048 + i * 512]),
                                         16, 0, 0);
    }
    const short* bufp = smB[p];
#pragma unroll
    for (int h = 0; h < 2; ++h) {
      bf16x8 B0[4], B1[4];
#pragma unroll
      for (int t = 0; t < 4; ++t) {
        const short* lb = bufp + ((h * 4 + t) * 16 + col) * 64;
        B0[t] = *(const bf16x8*)(lb + s0off);
        B1[t] = *(const bf16x8*)(lb + s1off);
      }
#pragma unroll
      for (int t = 0; t < 4; ++t) {
        int code = codeB + s * 128 + (h * 4 + t) * 16;
#pragma unroll
        for (int f = 0; f < 4; ++f) {
          f32x4 acc = {0.f, 0.f, 0.f, 0.f};
          acc = __builtin_amdgcn_mfma_f32_16x16x32_bf16(A0[f], B0[t], acc, 0, 0, 0);
          acc = __builtin_amdgcn_mfma_f32_16x16x32_bf16(A1[f], B1[t], acc, 0, 0, 0);
          float dmax = fmaxf(fmaxf(acc[0] - th[f][0], acc[1] - th[f][1]),
                             fmaxf(acc[2] - th[f][2], acc[3] - th[f][3]));
          if (dmax >= 0.f) {
#pragma unroll
            for (int r = 0; r < 4; ++r) {
              if (acc[r] >= th[f][r]) {
                int tok = tokBase + f * 16 + quad * 4 + r;
                int pos = atomicAdd(&g_candcnt[tok], 1);
                if (pos < CAP) g_cand[tok * CAP + pos] = code;
              }
            }
          }
        }
      }
    }
    __syncthreads();
    p ^= 1;
  }
}

// k_scan (r26, unchanged): worklist of cnt>=2 tokens; 1 atomic/block.
__global__ __launch_bounds__(256) void k_scan() {
  __shared__ int flags[256];
  __shared__ int sbase;
  int tid = threadIdx.x;
  int tok = blockIdx.x * 256 + tid;
  int flag = (g_candcnt[tok] >= 2) ? 1 : 0;
  flags[tid] = flag;
  __syncthreads();
  if (tid == 0) {
    int run = 0;
    for (int i = 0; i < 256; ++i) {
      int f = flags[i];
      flags[i] = run;  // exclusive prefix
      run += f;
    }
    sbase = atomicAdd(&g_wln, run);
  }
  __syncthreads();
  if (flag) g_wl[sbase + flags[tid]] = tok;
}

// per-candidate arbiter body (fp64 math and order identical to r24/r29)
#define ARB_BODY(CODE)                                                            \
  {                                                                               \
    double s0 = 0.0, s1 = 0.0, s2 = 0.0, s3 = 0.0;                                \
    _Pragma("unroll") for (int kk = 0; kk < 16; ++kk) {                           \
      s0 = fma(WT[kk * 65 + lane], (double)cbl[wave][kk], s0);                    \
      s1 = fma(WT[(kk + 16) * 65 + lane], (double)cbl[wave][kk + 16], s1);        \
      s2 = fma(WT[(kk + 32) * 65 + lane], (double)cbl[wave][kk + 32], s2);        \
      s3 = fma(WT[(kk + 48) * 65 + lane], (double)cbl[wave][kk + 48], s3);        \
    }                                                                             \
    double qc = ((s0 + s1) + (s2 + s3)) + bj;                                     \
    double s = zj * qc, n2 = qc * qc;                                             \
    _Pragma("unroll") for (int o = 32; o > 0; o >>= 1) {                          \
      s += __shfl_xor(s, o, 64);                                                  \
      n2 += __shfl_xor(n2, o, 64);                                                \
    }                                                                             \
    double key = s / fmax(sqrt(n2), 1e-12);                                       \
    if (key > best || (key == best && (CODE) < bi)) { best = key; bi = (CODE); }  \
  }

// k_arb (r34): wave-per-token worklist (r24/r29 geometry, best measured) + 2-deep
// candidate prefetch pipeline. Codes shfl-distributed from one coalesced load (lanes
// 0-15) so the only vmcnt ops in the loop are our asm loads; drain c, issue c+1,
// compute c -> HBM fetch overlaps the fp64 chain. Math/order/tie-break identical.
__global__ __launch_bounds__(256) void k_arb(const float* __restrict__ z,
                                             const float* __restrict__ cb,
                                             const float* __restrict__ pw,
                                             const float* __restrict__ pb) {
  __shared__ double WT[64 * 65];  // WT[k*65+j] = W[j][k]
  __shared__ float cbl[4][64];
  int tid = threadIdx.x;
  int wave = tid >> 6, lane = tid & 63;
  for (int e = tid; e < 4096; e += 256) {
    int j = e >> 6, k = e & 63;
    WT[k * 65 + j] = (double)pw[e];
  }
  __syncthreads();

  int wln = g_wln;
  double bj = (double)pb[lane];
  int gwave = blockIdx.x * 4 + wave;

  for (int e = gwave; e < wln; e += 4096) {
    int tok = g_wl[e];
    int cnt = g_candcnt[tok];
    double zj = (double)z[(size_t)tok * 64 + lane];
    // all candidate codes in one coalesced load; distribute via shfl (no more
    // compiler-generated vmcnt loads inside the pipelined loop)
    int candv = g_cand[tok * CAP + (lane & 15)];
    double best = -1.0e300;
    int bi = 0x7FFFFFFF;
    int lim = (cnt <= CAP) ? cnt : 0;
    float rA, rB;
    int codeA = 0, codeBv = 0;
    if (lim > 0) {
      codeA = __shfl(candv, 0, 64);
      gld_f32(rA, cb + (size_t)codeA * 64 + lane);
    }
    int c = 0;
    while (c < lim) {
      // phase A: consume (rA, codeA); prefetch into (rB, codeBv)
      WAITV0;
      if (c + 1 < lim) {
        codeBv = __shfl(candv, c + 1, 64);
        gld_f32(rB, cb + (size_t)codeBv * 64 + lane);
      }
      cbl[wave][lane] = rA;
      ARB_BODY(codeA);
      ++c;
      if (c >= lim) break;
      // phase B: consume (rB, codeBv); prefetch into (rA, codeA)
      WAITV0;
      if (c + 1 < lim) {
        codeA = __shfl(candv, c + 1, 64);
        gld_f32(rA, cb + (size_t)codeA * 64 + lane);
      }
      cbl[wave][lane] = rB;
      ARB_BODY(codeBv);
      ++c;
    }
    if (cnt > CAP) {  // correctness insurance; empirically never fires (serial, r29 form)
      for (int code = 0; code < NCODES; ++code) {
        cbl[wave][lane] = cb[(size_t)code * 64 + lane];
        ARB_BODY(code);
      }
    }
    if (lane == 0) g_cand[tok * CAP] = bi;
  }
}

// k_out (r29, unchanged): 2048 blocks x 4 waves, wave owns 2 tokens; idx prefetched;
// PLAIN stores only (r31's lesson: no block-count-scaled ordered atomics).
__global__ __launch_bounds__(256) void k_out(const float* __restrict__ z,
                                             float* __restrict__ out0,
                                             float* __restrict__ out2) {
  __shared__ float ws[4];
  int tid = threadIdx.x;
  int wave = tid >> 6, lane = tid & 63;
  int base = blockIdx.x * 8 + wave * 2;
  int i0 = g_cand[(size_t)base * CAP];
  int i1 = g_cand[(size_t)(base + 1) * CAP];
  float q0 = g_qcb[(size_t)i0 * 64 + lane];
  float z0 = z[(size_t)base * 64 + lane];
  float q1 = g_qcb[(size_t)i1 * 64 + lane];
  float z1 = z[(size_t)(base + 1) * 64 + lane];
  float d0 = q0 - z0;
  float d1 = q1 - z1;
  out0[(size_t)base * 64 + lane] = z0 + d0;        // z + (q - z), ref op order
  out0[(size_t)(base + 1) * 64 + lane] = z1 + d1;
  if (lane == 0) {
    out2[base] = (float)i0;
    out2[base + 1] = (float)i1;
  }
  float lsum = fmaf(d0, d0, d1 * d1);
  float tot = wave_sum64(lsum);
  if (lane == 0) ws[wave] = tot;
  __syncthreads();
  if (tid == 0) g_partial[blockIdx.x] = ((ws[0] + ws[1]) + (ws[2] + ws[3]));
}

// k_loss (r29, unchanged): one wave sums the 2048 partials in fixed order -> out1.
__global__ void k_loss(float* __restrict__ out1) {
  int lane = threadIdx.x;
  float s = 0.f;
#pragma unroll
  for (int i = 0; i < 32; ++i) s += g_partial[lane + 64 * i];
  s = wave_sum64(s);
  if (lane == 0) out1[0] = 1.25f * s / 1048576.0f;  // commitment == codebook numerically
}

extern "C" void kernel_launch(void* const* d_in, const int* in_sizes, int n_in,
                              void* d_out, int out_size, void* d_ws, size_t ws_size,
                              hipStream_t stream) {
  const float* z = (const float*)d_in[0];
  const float* cb = (const float*)d_in[1];
  const float* pw = (const float*)d_in[2];
  const float* pb = (const float*)d_in[3];
  // d_in[4] (scale) unused: argmin invariant to positive scale

  float* out0 = (float*)d_out;
  float* out1 = out0 + (size_t)NTOK * DIM;
  float* out2 = out1 + 1;

  hipLaunchKernelGGL(k_prep, dim3(2048), dim3(256), 0, stream, cb, pw, pb, z);
  hipLaunchKernelGGL(k_mfma1, dim3(1024), dim3(256), 0, stream);
  hipLaunchKernelGGL(k_mfma2, dim3(1024), dim3(256), 0, stream);
  hipLaunchKernelGGL(k_scan, dim3(64), dim3(256), 0, stream);
  hipLaunchKernelGGL(k_arb, dim3(1024), dim3(256), 0, stream, z, cb, pw, pb);
  hipLaunchKernelGGL(k_out, dim3(2048), dim3(256), 0, stream, z, out0, out2);
  hipLaunchKernelGGL(k_loss, dim3(1), dim3(64), 0, stream, out1);
}